// Round 10
// baseline (326.910 us; speedup 1.0000x reference)
//
#include <hip/hip_runtime.h>

// B=16, NQ=NK=784, D_MODEL=512, H=8, DK=DV=64
#define SZX ((size_t)12544 * 512)   // elements of one [B*784, 512] matrix
#define WSEG ((size_t)262144)       // one 512x512 weight

typedef __attribute__((ext_vector_type(8))) short short8;
typedef __attribute__((ext_vector_type(4))) short short4s;
typedef __attribute__((ext_vector_type(4))) float floatx4;

typedef const __attribute__((address_space(1))) void* gas_cvp;
typedef __attribute__((address_space(3))) void* las_vp;

__device__ __forceinline__ void gl_lds16(const void* g, void* l) {
    __builtin_amdgcn_global_load_lds((gas_cvp)g, (las_vp)l, 16, 0, 0);
}

__device__ __forceinline__ unsigned short f2bf(float f) {
    unsigned int u = __float_as_uint(f);
    u += 0x7fffu + ((u >> 16) & 1u);   // RNE
    return (unsigned short)(u >> 16);
}

__device__ __forceinline__ short8 cvt8(floatx4 a, floatx4 b) {
    short8 r;
    r[0] = (short)f2bf(a[0]); r[1] = (short)f2bf(a[1]);
    r[2] = (short)f2bf(a[2]); r[3] = (short)f2bf(a[3]);
    r[4] = (short)f2bf(b[0]); r[5] = (short)f2bf(b[1]);
    r[6] = (short)f2bf(b[2]); r[7] = (short)f2bf(b[3]);
    return r;
}

__device__ __forceinline__ short8 lds_read8(const unsigned short* p) {
    // p is 8B-aligned (not 16B) — two b64 reads
    short4s a = *(const short4s*)p;
    short4s b = *(const short4s*)(p + 4);
    return __builtin_shufflevector(a, b, 0, 1, 2, 3, 4, 5, 6, 7);
}

#define MFMA16(a, b, c) __builtin_amdgcn_mfma_f32_16x16x32_bf16(a, b, c, 0, 0, 0)

// ---------------- weight transpose + convert: Wt[o][i] = bf16(W[i][o]) ------------
__global__ void transpose_cvt(const float* __restrict__ W0, const float* __restrict__ W1,
                              const float* __restrict__ W2, const float* __restrict__ W3,
                              unsigned short* __restrict__ out) {
    __shared__ float tile[32][33];
    const float* W = blockIdx.z == 0 ? W0 : blockIdx.z == 1 ? W1 : blockIdx.z == 2 ? W2 : W3;
    unsigned short* O = out + (size_t)blockIdx.z * WSEG;
    int x = blockIdx.x * 32 + threadIdx.x;
    int y0 = blockIdx.y * 32;
    for (int k = threadIdx.y; k < 32; k += 8)
        tile[k][threadIdx.x] = W[(size_t)(y0 + k) * 512 + x];
    __syncthreads();
    int xo = blockIdx.y * 32 + threadIdx.x;
    int yo0 = blockIdx.x * 32;
    for (int k = threadIdx.y; k < 32; k += 8)
        O[(size_t)(yo0 + k) * 512 + xo] = f2bf(tile[threadIdx.x][k]);
}

// ---------------- merged QKV projection GEMM, v8 (UNCHANGED — validated R8) -------
__global__ __launch_bounds__(256) void gemm_qkv(
    const float* __restrict__ Xq, const float* __restrict__ Xk,
    const float* __restrict__ Xv, const unsigned short* __restrict__ Wt,
    const float* __restrict__ bq, const float* __restrict__ bk, const float* __restrict__ bv,
    unsigned short* __restrict__ Qb, unsigned short* __restrict__ Kb,
    unsigned short* __restrict__ Vtb)
{
    __shared__ float Xls[128 * 64];            // 32KB f32 X-tile (granule-swizzled)
    __shared__ unsigned short Wls[128 * 64];   // 16KB bf16 W-tile (granule-swizzled)
    int z = blockIdx.z;
    const float* X = z == 0 ? Xq : z == 1 ? Xk : Xv;
    const unsigned short* Wz = Wt + (size_t)z * WSEG;
    const float* bias = z == 0 ? bq : z == 1 ? bk : bv;

    int tid = threadIdx.x;
    int lane = tid & 63, wave = tid >> 6;
    int wm = wave & 1, wn = wave >> 1;
    int c16 = lane & 15, g = lane >> 4;

    int G = blockIdx.x;
    int i98, i4;
    if (G < 384) { i98 = (G >> 5) * 8 + (G & 7); i4 = (G >> 3) & 3; }
    else         { int r = G - 384; i98 = 96 + (r & 1); i4 = r >> 1; }

    const float* Xbase = X + (size_t)i98 * 128 * 512;
    const unsigned short* Wbase = Wz + (size_t)i4 * 128 * 512;
    int tm = (z < 2) ? i98 : i4;
    int tn = (z < 2) ? i4 : i98;
    int wx = (z < 2) ? wm : wn;
    int ww = (z < 2) ? wn : wm;

    floatx4 acc[4][4];
#pragma unroll
    for (int i = 0; i < 4; i++)
#pragma unroll
        for (int j = 0; j < 4; j++) acc[i][j] = (floatx4){0.f, 0.f, 0.f, 0.f};

    for (int kb = 0; kb < 8; ++kb) {
        int k0 = kb * 64;
#pragma unroll
        for (int rep = 0; rep < 8; ++rep) {
            int slot = rep * 256 + tid;
            int row = slot >> 4, gc = slot & 15;
            int src = (gc & 8) | ((gc & 7) ^ (row & 7));
            gl_lds16(Xbase + (size_t)row * 512 + k0 + src * 4, &Xls[slot * 4]);
        }
#pragma unroll
        for (int rep = 0; rep < 4; ++rep) {
            int slot = rep * 256 + tid;
            int row = slot >> 3, gc = slot & 7;
            int src = gc ^ (row & 7);
            gl_lds16(Wbase + (size_t)row * 512 + k0 + src * 8, &Wls[slot * 8]);
        }
        __syncthreads();

#pragma unroll
        for (int kk = 0; kk < 2; ++kk) {
            short8 xf[4], wf[4];
#pragma unroll
            for (int i = 0; i < 4; i++) {
                int row = wx * 64 + i * 16 + c16;
                int sw = row & 7;
                int g0 = kk * 8 + 2 * g;
                int p0 = (g0 & 8) | ((g0 & 7) ^ sw);
                int p1 = ((g0 + 1) & 8) | (((g0 + 1) & 7) ^ sw);
                floatx4 a  = *(const floatx4*)&Xls[row * 64 + p0 * 4];
                floatx4 b2 = *(const floatx4*)&Xls[row * 64 + p1 * 4];
                xf[i] = cvt8(a, b2);
            }
#pragma unroll
            for (int j = 0; j < 4; j++) {
                int row = ww * 64 + j * 16 + c16;
                int gl = kk * 4 + g;
                wf[j] = *(const short8*)&Wls[row * 64 + (gl ^ (row & 7)) * 8];
            }
            if (z < 2) {
#pragma unroll
                for (int i = 0; i < 4; i++)
#pragma unroll
                    for (int j = 0; j < 4; j++)
                        acc[i][j] = MFMA16(xf[i], wf[j], acc[i][j]);
            } else {
#pragma unroll
                for (int i = 0; i < 4; i++)
#pragma unroll
                    for (int j = 0; j < 4; j++)
                        acc[i][j] = MFMA16(wf[i], xf[j], acc[i][j]);
            }
        }
        __syncthreads();
    }

#pragma unroll
    for (int j = 0; j < 4; j++) {
        int n = tn * 128 + wn * 64 + j * 16 + c16;
        int bi = n / 784, nn = n - bi * 784;         // z==2 only
        float bvn = (z < 2) ? bias[n] : 0.f;
#pragma unroll
        for (int i = 0; i < 4; i++) {
#pragma unroll
            for (int r4 = 0; r4 < 4; r4++) {
                int m = tm * 128 + wm * 64 + i * 16 + g * 4 + r4;
                float v = acc[i][j][r4] + ((z < 2) ? bvn : bias[m]);
                if (z == 0)      Qb[(size_t)m * 512 + n] = f2bf(v);
                else if (z == 1) Kb[(size_t)m * 512 + n] = f2bf(v);
                else {
                    int h = m >> 6, d = m & 63;
                    Vtb[(((size_t)bi * 8 + h) * 64 + d) * 784 + nn] = f2bf(v);
                }
            }
        }
    }
}

// ---------------- output projection, v9 (UNCHANGED — validated R9) ----------------
__global__ __launch_bounds__(256) void gemm_out(
    const unsigned short* __restrict__ Wto, const unsigned short* __restrict__ ctx,
    const float* __restrict__ bo, float* __restrict__ out)
{
    __shared__ unsigned short Als[128 * 64];   // 16KB Wto tile (granule-swizzled)
    __shared__ unsigned short Bls[128 * 64];   // 16KB ctx tile (granule-swizzled)
    int tid = threadIdx.x;
    int lane = tid & 63, wave = tid >> 6;
    int wm = wave & 1, wn = wave >> 1;
    int c16 = lane & 15, g = lane >> 4;

    int G = blockIdx.x;
    int i98, i4;
    if (G < 384) { i98 = (G >> 5) * 8 + (G & 7); i4 = (G >> 3) & 3; }
    else         { int r = G - 384; i98 = 96 + (r & 1); i4 = r >> 1; }
    int tm = i4, tn = i98;

    const unsigned short* Abase = Wto + (size_t)tm * 128 * 512;
    const unsigned short* Bbase = ctx + (size_t)tn * 128 * 512;

    floatx4 acc[4][4];
#pragma unroll
    for (int i = 0; i < 4; i++)
#pragma unroll
        for (int j = 0; j < 4; j++) acc[i][j] = (floatx4){0.f, 0.f, 0.f, 0.f};

    for (int kb = 0; kb < 8; ++kb) {
        int k0 = kb * 64;
#pragma unroll
        for (int rep = 0; rep < 4; ++rep) {
            int slot = rep * 256 + tid;
            int row = slot >> 3, gc = slot & 7;
            int src = gc ^ (row & 7);
            gl_lds16(Abase + (size_t)row * 512 + k0 + src * 8, &Als[slot * 8]);
            gl_lds16(Bbase + (size_t)row * 512 + k0 + src * 8, &Bls[slot * 8]);
        }
        __syncthreads();

#pragma unroll
        for (int kk = 0; kk < 2; ++kk) {
            short8 af[4], bfr[4];
#pragma unroll
            for (int i = 0; i < 4; i++) {
                int row = wm * 64 + i * 16 + c16;
                int gl = kk * 4 + g;
                af[i] = *(const short8*)&Als[row * 64 + (gl ^ (row & 7)) * 8];
            }
#pragma unroll
            for (int j = 0; j < 4; j++) {
                int row = wn * 64 + j * 16 + c16;
                int gl = kk * 4 + g;
                bfr[j] = *(const short8*)&Bls[row * 64 + (gl ^ (row & 7)) * 8];
            }
#pragma unroll
            for (int i = 0; i < 4; i++)
#pragma unroll
                for (int j = 0; j < 4; j++)
                    acc[i][j] = MFMA16(af[i], bfr[j], acc[i][j]);
        }
        __syncthreads();
    }

#pragma unroll
    for (int j = 0; j < 4; j++) {
        int n = tn * 128 + wn * 64 + j * 16 + c16;
        int bi = n / 784, q = n - bi * 784;
#pragma unroll
        for (int i = 0; i < 4; i++) {
#pragma unroll
            for (int r4 = 0; r4 < 4; r4++) {
                int m = tm * 128 + wm * 64 + i * 16 + g * 4 + r4;
                out[((size_t)bi * 512 + m) * 784 + q] = acc[i][j][r4] + bo[m];
            }
        }
    }
}

// ---------------- fused attention v10: KEY-split waves ----------------------------
// R1 lesson: splitting Q duplicates K/V/corr traffic (regressed). This splits K:
// waves pair up on one (b, h, q-tile); wave khalf processes key-tiles
// it = khalf, khalf+2, ... (disjoint -> total K/V/corr bytes UNCHANGED; FETCH
// ~59MB is the tripwire — >70MB means duplication). Per-wave serial chain halves
// (6-7 iters vs 13); wave count doubles (6400, grid 1600 blocks = 2 heads x
// 2 khalves x 4 waves). The no-max softmax is additive, so partials combine
// exactly: khalf=1 publishes partial O (32x64 f32, pad-68) + partial l via LDS;
// one barrier; khalf=0 adds, normalizes, stores. FP sum order changes -> absmax
// may move slightly (threshold 4.39e-06 has 4.6x headroom).
// Blocks sharing a (b,qt) corr slab have ids 400 apart = same XCD (mod 8).
__global__ __launch_bounds__(256) void attn_kernel(
    const unsigned short* __restrict__ Qb,
    const unsigned short* __restrict__ Kb,
    const unsigned short* __restrict__ Vtb,
    const float* __restrict__ corr,
    unsigned short* __restrict__ ctx)
{
    __shared__ unsigned short Plds[4][2][16][68];   // per-wave P buffer (17408 B)
    __shared__ float Ox[2][32][68];                 // per-head-pair O exchange (17408 B)
    __shared__ float Lx[2][32];                     // per-head-pair l exchange (256 B)
    int b = blockIdx.x, qt = blockIdx.y, hq = blockIdx.z;
    int tid = threadIdx.x;
    int lane = tid & 63, w = tid >> 6;
    int hp = w >> 1, khalf = w & 1;                 // head-in-pair, key-half
    int h = hq * 2 + hp;
    int c16 = lane & 15, g = lane >> 4;
    int q0 = qt * 32;

    short8 aq[2][2];
#pragma unroll
    for (int u = 0; u < 2; ++u) {
        int row = q0 + u * 16 + c16; row = row < 784 ? row : 783;
        const unsigned short* qp = Qb + (size_t)(b * 784 + row) * 512 + h * 64 + g * 8;
        aq[u][0] = *(const short8*)qp;
        aq[u][1] = *(const short8*)(qp + 32);
    }

    floatx4 o[2][4];
    float l[2][4];
#pragma unroll
    for (int u = 0; u < 2; ++u)
#pragma unroll
        for (int nt = 0; nt < 4; nt++) { o[u][nt] = (floatx4){0.f, 0.f, 0.f, 0.f}; l[u][nt] = 0.f; }

    const float* corrb = corr + (size_t)b * 784 * 784;
    int crow[2][4];
#pragma unroll
    for (int u = 0; u < 2; ++u)
#pragma unroll
        for (int r = 0; r < 4; ++r) {
            int rr = q0 + u * 16 + g * 4 + r; rr = rr < 784 ? rr : 783;
            crow[u][r] = rr * 784;
        }

    const unsigned short* Vh = Vtb + ((size_t)(b * 8 + h)) * 64 * 784;
    const unsigned short* Kh = Kb + (size_t)b * 784 * 512 + h * 64;

    // interleaved key-tile split: khalf=0 -> it 0,2,..,12 ; khalf=1 -> 1,3,..,11
    for (int it = khalf; it < 13; it += 2) {
        int k0 = it * 64;
        // QK^T: s[u][t] over 64 keys
        floatx4 s[2][4];
#pragma unroll
        for (int t = 0; t < 4; ++t) {
            int key = k0 + t * 16 + c16; key = key < 784 ? key : 783;
            const unsigned short* kp = Kh + (size_t)key * 512 + g * 8;
            short8 k0f = *(const short8*)kp;
            short8 k1f = *(const short8*)(kp + 32);
#pragma unroll
            for (int u = 0; u < 2; ++u) {
                floatx4 zz = (floatx4){0.f, 0.f, 0.f, 0.f};
                zz = MFMA16(aq[u][0], k0f, zz);
                zz = MFMA16(aq[u][1], k1f, zz);
                s[u][t] = zz;
            }
        }
        // p = exp(s/8 + corr)  (no max: logits bounded by ~6)
        unsigned short* pbase = &Plds[w][0][0][0];
#pragma unroll
        for (int u = 0; u < 2; ++u)
#pragma unroll
            for (int t = 0; t < 4; ++t) {
                int key = k0 + t * 16 + c16;
                bool valid = key < 784;
                int kc = valid ? key : 783;
#pragma unroll
                for (int r = 0; r < 4; ++r) {
                    float cv = corrb[crow[u][r] + kc];
                    float sv = fmaf(s[u][t][r], 0.125f, cv);
                    float pv = valid ? __expf(sv) : 0.f;
                    l[u][r] += pv;
                    pbase[(u * 16 + g * 4 + r) * 68 + t * 16 + c16] = f2bf(pv);
                }
            }
        // P·V
#pragma unroll
        for (int u = 0; u < 2; ++u) {
            const unsigned short* pr = &Plds[w][u][c16][0];
            short8 pa0 = lds_read8(pr + g * 8);
            short8 pa1 = lds_read8(pr + 32 + g * 8);
#pragma unroll
            for (int nt = 0; nt < 4; ++nt) {
                int d = nt * 16 + c16;
                const unsigned short* vp = Vh + (size_t)d * 784 + k0 + g * 8;
                short8 v0 = *(const short8*)vp;
                short8 v1 = *(const short8*)(vp + 32);
                o[u][nt] = MFMA16(pa0, v0, o[u][nt]);
                o[u][nt] = MFMA16(pa1, v1, o[u][nt]);
            }
        }
    }

    // intra-wave key-reduce of l (over the 16 c16 lanes; all lanes end with row sum)
#pragma unroll
    for (int u = 0; u < 2; ++u)
#pragma unroll
        for (int r = 0; r < 4; ++r) {
            float lv = l[u][r];
            lv += __shfl_xor(lv, 1);
            lv += __shfl_xor(lv, 2);
            lv += __shfl_xor(lv, 4);
            lv += __shfl_xor(lv, 8);
            l[u][r] = lv;
        }

    // cross-wave combine: khalf=1 publishes partials, khalf=0 merges + stores
    if (khalf == 1) {
        if (c16 == 0) {
#pragma unroll
            for (int u = 0; u < 2; ++u)
#pragma unroll
                for (int r = 0; r < 4; ++r)
                    Lx[hp][u * 16 + g * 4 + r] = l[u][r];
        }
#pragma unroll
        for (int u = 0; u < 2; ++u)
#pragma unroll
            for (int nt = 0; nt < 4; ++nt)
#pragma unroll
                for (int r = 0; r < 4; ++r)
                    Ox[hp][u * 16 + g * 4 + r][nt * 16 + c16] = o[u][nt][r];
    }
    __syncthreads();
    if (khalf == 0) {
#pragma unroll
        for (int u = 0; u < 2; ++u)
#pragma unroll
            for (int r = 0; r < 4; ++r)
                l[u][r] = 1.0f / (l[u][r] + Lx[hp][u * 16 + g * 4 + r]);
#pragma unroll
        for (int u = 0; u < 2; ++u)
#pragma unroll
            for (int r = 0; r < 4; ++r) {
                int row = q0 + u * 16 + g * 4 + r;
                if (row < 784) {
#pragma unroll
                    for (int nt = 0; nt < 4; ++nt) {
                        float val = o[u][nt][r] + Ox[hp][u * 16 + g * 4 + r][nt * 16 + c16];
                        ctx[(size_t)(b * 784 + row) * 512 + h * 64 + nt * 16 + c16] =
                            f2bf(val * l[u][r]);
                    }
                }
            }
    }
}

extern "C" void kernel_launch(void* const* d_in, const int* in_sizes, int n_in,
                              void* d_out, int out_size, void* d_ws, size_t ws_size,
                              hipStream_t stream) {
    (void)in_sizes; (void)n_in; (void)out_size; (void)ws_size;
    const float* queries = (const float*)d_in[0];
    const float* keys    = (const float*)d_in[1];
    const float* values  = (const float*)d_in[2];
    const float* corr    = (const float*)d_in[3];
    const float* Wq = (const float*)d_in[4];
    const float* bq = (const float*)d_in[5];
    const float* Wk = (const float*)d_in[6];
    const float* bk = (const float*)d_in[7];
    const float* Wv = (const float*)d_in[8];
    const float* bv = (const float*)d_in[9];
    const float* Wo = (const float*)d_in[10];
    const float* bo = (const float*)d_in[11];

    // workspace: Qb, Kb, Vtb, ctx (bf16, SZX each) + Wt (4 x WSEG bf16) = 53.5 MB
    unsigned short* Qb  = (unsigned short*)d_ws;
    unsigned short* Kb  = Qb + SZX;
    unsigned short* Vtb = Kb + SZX;
    unsigned short* ctx = Vtb + SZX;
    unsigned short* Wt  = ctx + SZX;

    transpose_cvt<<<dim3(16, 16, 4), dim3(32, 8), 0, stream>>>(Wq, Wk, Wv, Wo, Wt);
    gemm_qkv<<<dim3(392, 1, 3), 256, 0, stream>>>(queries, keys, values, Wt,
                                                  bq, bk, bv, Qb, Kb, Vtb);
    attn_kernel<<<dim3(16, 25, 4), 256, 0, stream>>>(Qb, Kb, Vtb, corr, ctx);
    gemm_out<<<dim3(392), 256, 0, stream>>>(Wt + 3 * WSEG, ctx, bo, (float*)d_out);
}